// Round 6
// baseline (401.467 us; speedup 1.0000x reference)
//
#include <hip/hip_runtime.h>

// GraphSAGE x3 + BN(train stats) + ReLU + head. bf16 features/weights,
// fp32 MFMA accumulation, fp32 BN stats.
// R13: aggb tail-killer — BSZ 96 (3 nodes/group exact) + dynamic node
// stealing via LDS counter (degree-variance balance; deterministic output).
// BPART 512 (shorter partition chunks), grid-stride x-conversion in prep.
// Everything else frozen from R12 (best=390.8us).

#define N_NODES 100000
#define N_EDGES 1250000
#define NB 1042         // buckets (NB*BSZ = 100032 >= N, no empty blocks)
#define BSZ 96          // dst nodes per bucket (96 = 32 groups x 3 nodes)
#define CAP 1536        // slots per bucket (mean 1200, sigma ~35)
#define BPART 512       // partition chunks (hist/scatter blocks)
#define PREP_X 1024     // grid-stride blocks for x conversion
#define INVN (1.0f / 100000.0f)

typedef short bf16x8 __attribute__((ext_vector_type(8)));
typedef float f32x4 __attribute__((ext_vector_type(4)));
typedef unsigned short u16x8 __attribute__((ext_vector_type(8)));
typedef unsigned short u16x4 __attribute__((ext_vector_type(4)));

__device__ __forceinline__ float bf2f(unsigned short u) {
  union { unsigned int i; float f; } c; c.i = ((unsigned int)u) << 16; return c.f;
}
__device__ __forceinline__ unsigned short f2bf(float f) {
  union { float f; unsigned int i; } c; c.f = f;
  unsigned int r = (c.i + 0x7FFFu + ((c.i >> 16) & 1u)) >> 16;  // RNE
  return (unsigned short)r;
}
// stats layout per layer: [4 replicas][2][128] = 1024 floats
__device__ __forceinline__ void bn_st(const float* stats, const float* gam,
                                      const float* bet, int c, float& s, float& t) {
  float sum = stats[c] + stats[256 + c] + stats[512 + c] + stats[768 + c];
  float sq  = stats[128 + c] + stats[384 + c] + stats[640 + c] + stats[896 + c];
  float mu = sum * INVN;
  float var = sq * INVN - mu * mu;
  s = gam[c] * rsqrtf(var + 1e-5f);
  t = bet[c] - mu * s;
}
// async global->LDS, 16B per lane; lds base must be wave-uniform.
__device__ __forceinline__ void gload_lds16(const void* g, void* l) {
  __builtin_amdgcn_global_load_lds(
      (const __attribute__((address_space(1))) unsigned int*)g,
      (__attribute__((address_space(3))) unsigned int*)l, 16, 0, 0);
}

// ----------------- prep: f2bf(x) + weight transpose + init + hist ---------
__global__ __launch_bounds__(256) void k_prep(
    const float* __restrict__ x, unsigned short* __restrict__ x16,
    const float* __restrict__ W0s, const float* __restrict__ W0n,
    const float* __restrict__ W1s, const float* __restrict__ W1n,
    const float* __restrict__ W2s, const float* __restrict__ W2n,
    unsigned short* __restrict__ wt, float* __restrict__ stats3,
    const int* __restrict__ dst, int* __restrict__ hist, int E) {
  __shared__ int hh[NB];
  int blk = blockIdx.x, t = threadIdx.x;
  if (blk < PREP_X) {
    // grid-stride over N*64/4 = 1.6M float4s
    for (int i = blk * 256 + t; i < N_NODES * 16; i += PREP_X * 256) {
      float4 v = ((const float4*)x)[i];
      u16x4 o;
      o.x = f2bf(v.x); o.y = f2bf(v.y); o.z = f2bf(v.z); o.w = f2bf(v.w);
      ((u16x4*)x16)[i] = o;
    }
  } else if (blk < PREP_X + 320) {
    int i = (blk - PREP_X) * 256 + t;
    if (i < 16384) {
      const float* W = (i < 8192) ? W0s : W0n;
      unsigned short* o = wt + (i < 8192 ? 0 : 8192);
      int j = i & 8191;
      int c = j >> 6, k = j & 63;
      o[j] = f2bf(W[k * 128 + c]);
    } else {
      int j = i - 16384;
      int sel = j >> 14;
      j &= 16383;
      const float* W = (sel == 0) ? W1s : (sel == 1) ? W1n : (sel == 2) ? W2s : W2n;
      unsigned short* o = wt + 16384 + sel * 16384;
      int c = j >> 7, k = j & 127;
      o[j] = f2bf(W[k * 128 + c]);
    }
  } else if (blk == PREP_X + 320) {
    for (int i = t; i < 3 * 1024; i += 256) stats3[i] = 0.f;
  } else {
    // per-chunk histogram (merged k_hist)
    int hb = blk - (PREP_X + 321);
    int chunk = (E + BPART - 1) / BPART;
    int start = hb * chunk;
    int end = min(E, start + chunk);
    for (int b = t; b < NB; b += 256) hh[b] = 0;
    __syncthreads();
    for (int e = start + t; e < end; e += 256) atomicAdd(&hh[dst[e] / BSZ], 1);
    __syncthreads();
    for (int b = t; b < NB; b += 256) hist[hb * NB + b] = hh[b];
  }
}

// ----------------- partition pass 2: per-bucket scan over chunks -----------
__global__ __launch_bounds__(256) void k_scan(const int* __restrict__ hist,
                                              int* __restrict__ base,
                                              int* __restrict__ gcursor) {
  int bb = blockIdx.x * 256 + threadIdx.x;
  if (bb >= NB) return;
  int run = 0;
  for (int r0 = 0; r0 < BPART; r0 += 16) {
    int v[16];
    #pragma unroll
    for (int u = 0; u < 16; u++) v[u] = hist[(r0 + u) * NB + bb];
    #pragma unroll
    for (int u = 0; u < 16; u++) { base[(r0 + u) * NB + bb] = run; run += v[u]; }
  }
  gcursor[bb] = run;
}

// ----------------- partition pass 3: scatter with LDS cursors --------------
__global__ __launch_bounds__(256) void k_scatter(const int* __restrict__ src,
                                                 const int* __restrict__ dst,
                                                 const int* __restrict__ base,
                                                 unsigned int* __restrict__ part, int E) {
  __shared__ int cur[NB];
  int t = threadIdx.x;
  int chunk = (E + BPART - 1) / BPART;
  int start = blockIdx.x * chunk;
  int end = min(E, start + chunk);
  for (int b = t; b < NB; b += 256) cur[b] = base[blockIdx.x * NB + b];
  __syncthreads();
  for (int e = start + t; e < end; e += 256) {
    int d = dst[e];
    int b = d / BSZ;
    int pos = atomicAdd(&cur[b], 1);
    if ((unsigned)pos < (unsigned)CAP)
      part[(size_t)b * CAP + pos] = (unsigned)src[e] | ((unsigned)(d - b * BSZ) << 17);
  }
}

// ----------------- bucketed mean aggregation (LDS CSR + reg accum) --------
// 512 threads, 2-edge unroll, per-edge BN+ReLU fused (free under the
// gather's memory bound). R13: dynamic node stealing — groups pull nodes
// from an LDS counter; removes the max-over-groups Poisson-degree tail.
// Output deterministic (per-node accumulation order fixed by eord).
template <int DIM>
__global__ __launch_bounds__(512) void k_aggb(const unsigned short* __restrict__ h,
                                              const unsigned int* __restrict__ part,
                                              const int* __restrict__ gcursor,
                                              unsigned short* __restrict__ neigh, int n,
                                              const float* __restrict__ statsP,
                                              const float* __restrict__ gamP,
                                              const float* __restrict__ betP) {
  __shared__ unsigned eraw[CAP];
  __shared__ unsigned eord[CAP];
  __shared__ int cnt[BSZ], offv[BSZ], cur[BSZ];
  __shared__ int scan[128];
  __shared__ int stealCtr;
  int t = threadIdx.x;
  int bkt = blockIdx.x;
  int node0 = bkt * BSZ;
  int nn = min(BSZ, n - node0);
  if (nn <= 0) return;
  if (t < BSZ) cnt[t] = 0;
  if (t == 0) stealCtr = 0;
  __syncthreads();
  int ec = gcursor[bkt];
  ec = max(0, min(ec, CAP));
  for (int i = t; i < ec; i += 512) {
    unsigned w = part[(size_t)bkt * CAP + i];
    eraw[i] = w;
    atomicAdd(&cnt[w >> 17], 1);
  }
  __syncthreads();
  if (t < 128) scan[t] = (t < BSZ) ? cnt[t] : 0;
  __syncthreads();
  #pragma unroll
  for (int o = 1; o < 128; o <<= 1) {
    int x = 0;
    if (t < 128 && t >= o) x = scan[t - o];
    __syncthreads();
    if (t < 128) scan[t] += x;
    __syncthreads();
  }
  if (t < BSZ) { offv[t] = scan[t] - cnt[t]; cur[t] = scan[t] - cnt[t]; }
  __syncthreads();
  for (int i = t; i < ec; i += 512) {
    unsigned w = eraw[i];
    int p = atomicAdd(&cur[w >> 17], 1);
    eord[p] = w & 0x1FFFF;
  }
  __syncthreads();
  const int G = DIM / 8;
  int li = t % G;
  float sreg[8], treg[8];
  bool bn = (statsP != nullptr);
  if (bn) {
    #pragma unroll
    for (int k = 0; k < 8; k++) bn_st(statsP, gamP, betP, li * 8 + k, sreg[k], treg[k]);
  }
  for (;;) {
    int nd0 = 0;
    if (li == 0) nd0 = atomicAdd(&stealCtr, 1);
    int nd = __shfl(nd0, 0, G);  // broadcast group-leader's pull
    if (nd >= nn) break;
    int s = offv[nd], c = cnt[nd];
    int e = s + c;
    float acc[8] = {0.f, 0.f, 0.f, 0.f, 0.f, 0.f, 0.f, 0.f};
    int j = s;
    for (; j + 2 <= e; j += 2) {
      int sn0 = eord[j], sn1 = eord[j + 1];
      u16x8 v0 = *(const u16x8*)&h[(size_t)sn0 * DIM + li * 8];
      u16x8 v1 = *(const u16x8*)&h[(size_t)sn1 * DIM + li * 8];
      if (bn) {
        #pragma unroll
        for (int k = 0; k < 8; k++)
          acc[k] += fmaxf(fmaf(bf2f(v0[k]), sreg[k], treg[k]), 0.f)
                  + fmaxf(fmaf(bf2f(v1[k]), sreg[k], treg[k]), 0.f);
      } else {
        #pragma unroll
        for (int k = 0; k < 8; k++) acc[k] += bf2f(v0[k]) + bf2f(v1[k]);
      }
    }
    if (j < e) {
      int sn = eord[j];
      u16x8 v = *(const u16x8*)&h[(size_t)sn * DIM + li * 8];
      if (bn) {
        #pragma unroll
        for (int k = 0; k < 8; k++)
          acc[k] += fmaxf(fmaf(bf2f(v[k]), sreg[k], treg[k]), 0.f);
      } else {
        #pragma unroll
        for (int k = 0; k < 8; k++) acc[k] += bf2f(v[k]);
      }
    }
    float inv = 1.0f / fmaxf((float)c, 1.0f);
    u16x8 o;
    #pragma unroll
    for (int k = 0; k < 8; k++) o[k] = f2bf(acc[k] * inv);
    *(u16x8*)&neigh[(size_t)(node0 + nd) * DIM + li * 8] = o;
  }
}

// ----------------- MFMA GEMM: C = bnrelu?(A1)@W1 + A2@W2 + bias, + stats --
// 128x128 tile, BK=32, 256 threads. 2-phase double-buffered pipeline:
// issue next-tile loads before current MFMA (T3 minimum), BN reg-stage
// for the A1 half (issue-early load / write-late BN, T14).
__global__ __launch_bounds__(256) void k_gemm_mfma(
    const unsigned short* __restrict__ A1, const unsigned short* __restrict__ W1t,
    const unsigned short* __restrict__ A2, const unsigned short* __restrict__ W2t,
    const float* __restrict__ bias, unsigned short* __restrict__ C,
    float* __restrict__ stats, int M, int din,
    const float* __restrict__ statsP, const float* __restrict__ gamP,
    const float* __restrict__ betP) {
  __shared__ unsigned short As[2][128 * 32];
  __shared__ unsigned short Bs[2][128 * 32];
  __shared__ float redS[4 * 128];
  __shared__ float redQ[4 * 128];
  __shared__ float sBN[128], tBN[128];

  int t = threadIdx.x;
  int lane = t & 63, w = t >> 6;
  int l15 = lane & 15, quad = lane >> 4;
  int row0 = blockIdx.x * 128;
  bool hasBN = (statsP != nullptr);
  if (hasBN && t < 128) bn_st(statsP, gamP, betP, t, sBN[t], tBN[t]);
  if (hasBN) __syncthreads();  // publish sBN/tBN before first BN stage

  const int steps1 = din >> 5;  // k-steps per half
  const int S = steps1 * 2;

  f32x4 acc[2][8];
  #pragma unroll
  for (int rt = 0; rt < 2; rt++)
    #pragma unroll
    for (int ct = 0; ct < 8; ct++) acc[rt][ct] = (f32x4){0.f, 0.f, 0.f, 0.f};

  auto Aof  = [&](int s) { return (s < steps1) ? A1 : A2; };
  auto Wof  = [&](int s) { return (s < steps1) ? W1t : W2t; };
  auto k0of = [&](int s) { return ((s < steps1) ? s : s - steps1) << 5; };

  auto stageA = [&](int s, int bi) {  // async path; slack rows in-workspace
    const unsigned short* A = Aof(s); int k0 = k0of(s);
    #pragma unroll
    for (int i = 0; i < 2; i++) {
      int idx = t + 256 * i;
      int r = idx >> 2, prt = idx & 3;
      gload_lds16(&A[(size_t)(row0 + r) * din + k0 + prt * 8],
                  &As[bi][(i * 256 + w * 64) * 8]);
    }
  };
  auto stageB = [&](int s, int bi) {
    const unsigned short* Wt = Wof(s); int k0 = k0of(s);
    #pragma unroll
    for (int i = 0; i < 2; i++) {
      int idx = t + 256 * i;
      int r = idx >> 2, prt = idx & 3;
      gload_lds16(&Wt[(size_t)r * din + k0 + prt * 8],
                  &Bs[bi][(i * 256 + w * 64) * 8]);
    }
  };
  u16x8 vreg[2];
  auto bnLoad = [&](int s) {  // issue-early: global -> regs (A1, BN layers)
    const unsigned short* A = Aof(s); int k0 = k0of(s);
    #pragma unroll
    for (int i = 0; i < 2; i++) {
      int idx = t + 256 * i;
      int r = idx >> 2, prt = idx & 3;
      // rows >= M read in-workspace slack (next buffer); masked at epilogue
      vreg[i] = *(const u16x8*)&A[(size_t)(row0 + r) * din + k0 + prt * 8];
    }
  };
  auto bnWrite = [&](int s, int bi) {  // write-late: BN+ReLU -> LDS
    int k0 = k0of(s);
    #pragma unroll
    for (int i = 0; i < 2; i++) {
      int idx = t + 256 * i;
      int prt = idx & 3;
      u16x8 v = vreg[i];
      #pragma unroll
      for (int j = 0; j < 8; j++) {
        int c = k0 + prt * 8 + j;
        v[j] = f2bf(fmaxf(fmaf(bf2f(v[j]), sBN[c], tBN[c]), 0.f));
      }
      *(u16x8*)&As[bi][idx * 8] = v;
    }
  };

  // prologue: stage step 0 into buffer 0
  if (hasBN) { bnLoad(0); stageB(0, 0); bnWrite(0, 0); }
  else       { stageA(0, 0); stageB(0, 0); }
  __syncthreads();

  int cb = 0;
  for (int s = 0; s < S; s++) {
    int nb = cb ^ 1;
    bool haveNext = (s + 1 < S);
    bool bnNext = hasBN && (s + 1 < steps1);
    if (haveNext) {  // phase 1: issue next-tile loads before compute
      if (bnNext) bnLoad(s + 1);
      else        stageA(s + 1, nb);
      stageB(s + 1, nb);
    }
    // phase 2: compute current tile (load latency hides under this)
    bf16x8 af[2], bfr[8];
    #pragma unroll
    for (int rt = 0; rt < 2; rt++)
      af[rt] = *(const bf16x8*)&As[cb][(w * 32 + rt * 16 + l15) * 32 + quad * 8];
    #pragma unroll
    for (int ct = 0; ct < 8; ct++)
      bfr[ct] = *(const bf16x8*)&Bs[cb][(ct * 16 + l15) * 32 + quad * 8];
    #pragma unroll
    for (int rt = 0; rt < 2; rt++)
      #pragma unroll
      for (int ct = 0; ct < 8; ct++)
        acc[rt][ct] = __builtin_amdgcn_mfma_f32_16x16x32_bf16(af[rt], bfr[ct], acc[rt][ct], 0, 0, 0);
    // phase 3: finish next BN stage, publish buffer
    if (haveNext) {
      if (bnNext) bnWrite(s + 1, nb);
      __syncthreads();
    }
    cb = nb;
  }

  float bcol[8], ls[8], lq[8];
  #pragma unroll
  for (int ct = 0; ct < 8; ct++) {
    bcol[ct] = bias[ct * 16 + l15];
    ls[ct] = 0.f; lq[ct] = 0.f;
  }
  #pragma unroll
  for (int rt = 0; rt < 2; rt++) {
    #pragma unroll
    for (int r = 0; r < 4; r++) {
      int row = row0 + w * 32 + rt * 16 + quad * 4 + r;
      if (row < M) {
        #pragma unroll
        for (int ct = 0; ct < 8; ct++) {
          float v = acc[rt][ct][r] + bcol[ct];
          C[(size_t)row * 128 + ct * 16 + l15] = f2bf(v);
          ls[ct] += v; lq[ct] += v * v;
        }
      }
    }
  }
  #pragma unroll
  for (int ct = 0; ct < 8; ct++) {
    ls[ct] += __shfl_xor(ls[ct], 16); ls[ct] += __shfl_xor(ls[ct], 32);
    lq[ct] += __shfl_xor(lq[ct], 16); lq[ct] += __shfl_xor(lq[ct], 32);
  }
  if (quad == 0) {
    #pragma unroll
    for (int ct = 0; ct < 8; ct++) {
      redS[w * 128 + ct * 16 + l15] = ls[ct];
      redQ[w * 128 + ct * 16 + l15] = lq[ct];
    }
  }
  __syncthreads();
  if (t < 128) {
    float s = redS[t] + redS[128 + t] + redS[256 + t] + redS[384 + t];
    float q = redQ[t] + redQ[128 + t] + redQ[256 + t] + redQ[384 + t];
    int rep = (blockIdx.x & 3) * 256;  // 4 replicas: ~196-deep per address
    atomicAdd(&stats[rep + t], s);
    atomicAdd(&stats[rep + 128 + t], q);
  }
}

// ----------------- fused BN + ReLU + classifier -----------------
__global__ void k_final(const unsigned short* __restrict__ h,
                        const float* __restrict__ statsP, const float* __restrict__ gamP,
                        const float* __restrict__ betP, const float* __restrict__ Wc,
                        const float* __restrict__ bc, float* __restrict__ out, int n) {
  int lane = threadIdx.x & 63;
  int row = blockIdx.x * (blockDim.x >> 6) + (threadIdx.x >> 6);
  if (row >= n) return;
  float acc0 = 0.f, acc1 = 0.f;
  #pragma unroll
  for (int m = 0; m < 2; m++) {
    int c = lane + 64 * m;
    float s, tt;
    bn_st(statsP, gamP, betP, c, s, tt);
    float v = bf2f(h[(size_t)row * 128 + c]);
    v = fmaxf(fmaf(v, s, tt), 0.f);
    acc0 += v * Wc[c * 2 + 0];
    acc1 += v * Wc[c * 2 + 1];
  }
  #pragma unroll
  for (int off = 32; off > 0; off >>= 1) {
    acc0 += __shfl_down(acc0, off);
    acc1 += __shfl_down(acc1, off);
  }
  if (lane == 0) {
    out[row * 2 + 0] = acc0 + bc[0];
    out[row * 2 + 1] = acc1 + bc[1];
  }
}

extern "C" void kernel_launch(void* const* d_in, const int* in_sizes, int n_in,
                              void* d_out, int out_size, void* d_ws, size_t ws_size,
                              hipStream_t stream) {
  const float* x   = (const float*)d_in[0];
  const int* src   = (const int*)d_in[1];
  const int* dst   = (const int*)d_in[2];
  const float* Wself[3] = {(const float*)d_in[3], (const float*)d_in[8],  (const float*)d_in[13]};
  const float* bself[3] = {(const float*)d_in[4], (const float*)d_in[9],  (const float*)d_in[14]};
  const float* Wngh[3]  = {(const float*)d_in[5], (const float*)d_in[10], (const float*)d_in[15]};
  const float* gam[3]   = {(const float*)d_in[6], (const float*)d_in[11], (const float*)d_in[16]};
  const float* bet[3]   = {(const float*)d_in[7], (const float*)d_in[12], (const float*)d_in[17]};
  const float* Wc = (const float*)d_in[18];
  const float* bc = (const float*)d_in[19];
  float* out = (float*)d_out;

  const int N = N_NODES, E = N_EDGES;

  unsigned short* x16 = (unsigned short*)d_ws;        // N*64
  unsigned short* b0  = x16 + (size_t)N * 64;         // N*128 (neigh)
  unsigned short* b1  = b0 + (size_t)N * 128;
  unsigned short* b2  = b1 + (size_t)N * 128;
  unsigned short* wt  = b2 + (size_t)N * 128;         // 81920
  unsigned int* part  = (unsigned int*)(wt + 81920);  // NB*CAP
  int* gcursor  = (int*)(part + (size_t)NB * CAP);    // NB
  float* stats3 = (float*)(gcursor + NB);             // 3*1024

  // hist/base (BPART*NB ints = 2.1MB each) alias into b1 — b1 is first
  // written by gemm0, stream-ordered after scan/scatter consume them.
  int* hist = (int*)b1;
  int* base = hist + (size_t)BPART * NB;

  // ---- prep: x->bf16 (grid-stride), weights, stats zero, edge hist ----
  k_prep<<<PREP_X + 321 + BPART, 256, 0, stream>>>(
      x, x16, Wself[0], Wngh[0], Wself[1], Wngh[1], Wself[2], Wngh[2],
      wt, stats3, dst, hist, E);

  // ---- partition: scan -> scatter ----
  k_scan<<<(NB + 255) / 256, 256, 0, stream>>>(hist, base, gcursor);
  k_scatter<<<BPART, 256, 0, stream>>>(src, dst, base, part, E);

  const int gemmBlocks = (N + 127) / 128;

  // ---- layer 0 (din=64, raw x) ----
  k_aggb<64><<<NB, 512, 0, stream>>>(x16, part, gcursor, b0, N,
                                     nullptr, nullptr, nullptr);
  k_gemm_mfma<<<gemmBlocks, 256, 0, stream>>>(x16, wt + 0, b0, wt + 8192, bself[0],
                                              b1, stats3 + 0, N, 64,
                                              nullptr, nullptr, nullptr);

  // ---- layer 1 (din=128, BN0 per-edge in aggb + reg-staged in gemm) ----
  k_aggb<128><<<NB, 512, 0, stream>>>(b1, part, gcursor, b0, N,
                                      stats3 + 0, gam[0], bet[0]);
  k_gemm_mfma<<<gemmBlocks, 256, 0, stream>>>(b1, wt + 16384, b0, wt + 32768, bself[1],
                                              b2, stats3 + 1024, N, 128,
                                              stats3 + 0, gam[0], bet[0]);

  // ---- layer 2 (din=128, BN1) ----
  k_aggb<128><<<NB, 512, 0, stream>>>(b2, part, gcursor, b0, N,
                                      stats3 + 1024, gam[1], bet[1]);
  k_gemm_mfma<<<gemmBlocks, 256, 0, stream>>>(b2, wt + 49152, b0, wt + 65536, bself[2],
                                              b1, stats3 + 2048, N, 128,
                                              stats3 + 1024, gam[1], bet[1]);

  // ---- fused BN2 + ReLU + classifier ----
  k_final<<<(N + 3) / 4, 256, 0, stream>>>(b1, stats3 + 2048, gam[2], bet[2],
                                           Wc, bc, out, N);
}

// Round 8
// 375.935 us; speedup vs baseline: 1.0679x; 1.0679x over previous
//
#include <hip/hip_runtime.h>

// GraphSAGE x3 + BN(train stats) + ReLU + head. bf16 features/weights,
// fp32 MFMA accumulation, fp32 BN stats.
// R15 == R14 resubmit (bench infra failed twice; audit found no kernel
// fault mechanism). Fused layer — bucket == 64-row GEMM tile, 512 threads,
// ~31KB LDS -> 4 blocks/CU / 32 waves (fixes R11's 2-block starvation).
// Per block: CSR build -> steal-balanced gather into swizzled LDS neighT
// -> 64x128 MFMA GEMM (self A-frags from global L2-warm, neigh from LDS,
// W staged per k-step) -> C + stats. No inter-block deps. 7 launches.

#define N_NODES 100000
#define N_EDGES 1250000
#define NB 1563         // buckets == row tiles (64 dst nodes each)
#define BSZ 64
#define CAP 1024        // slots per bucket (mean 800, sigma ~28)
#define BPART 256       // partition chunks (hist/scatter blocks)
#define INVN (1.0f / 100000.0f)

typedef short bf16x8 __attribute__((ext_vector_type(8)));
typedef float f32x4 __attribute__((ext_vector_type(4)));
typedef unsigned short u16x8 __attribute__((ext_vector_type(8)));
typedef unsigned short u16x4 __attribute__((ext_vector_type(4)));

__device__ __forceinline__ float bf2f(unsigned short u) {
  union { unsigned int i; float f; } c; c.i = ((unsigned int)u) << 16; return c.f;
}
__device__ __forceinline__ unsigned short f2bf(float f) {
  union { float f; unsigned int i; } c; c.f = f;
  unsigned int r = (c.i + 0x7FFFu + ((c.i >> 16) & 1u)) >> 16;  // RNE
  return (unsigned short)r;
}
// stats layout per layer: [4 replicas][2][128] = 1024 floats
__device__ __forceinline__ void bn_st(const float* stats, const float* gam,
                                      const float* bet, int c, float& s, float& t) {
  float sum = stats[c] + stats[256 + c] + stats[512 + c] + stats[768 + c];
  float sq  = stats[128 + c] + stats[384 + c] + stats[640 + c] + stats[896 + c];
  float mu = sum * INVN;
  float var = sq * INVN - mu * mu;
  s = gam[c] * rsqrtf(var + 1e-5f);
  t = bet[c] - mu * s;
}
// async global->LDS, 16B per lane; lds base must be wave-uniform.
__device__ __forceinline__ void gload_lds16(const void* g, void* l) {
  __builtin_amdgcn_global_load_lds(
      (const __attribute__((address_space(1))) unsigned int*)g,
      (__attribute__((address_space(3))) unsigned int*)l, 16, 0, 0);
}

// ----------------- prep: f2bf(x) + weight transpose + init + hist ---------
__global__ __launch_bounds__(256) void k_prep(
    const float* __restrict__ x, unsigned short* __restrict__ x16,
    const float* __restrict__ W0s, const float* __restrict__ W0n,
    const float* __restrict__ W1s, const float* __restrict__ W1n,
    const float* __restrict__ W2s, const float* __restrict__ W2n,
    unsigned short* __restrict__ wt, float* __restrict__ stats3,
    const int* __restrict__ dst, int* __restrict__ hist, int E) {
  __shared__ int hh[NB];
  int blk = blockIdx.x, t = threadIdx.x;
  if (blk < 6250) {
    int i = blk * 256 + t;
    float4 v = ((const float4*)x)[i];
    u16x4 o;
    o.x = f2bf(v.x); o.y = f2bf(v.y); o.z = f2bf(v.z); o.w = f2bf(v.w);
    ((u16x4*)x16)[i] = o;
  } else if (blk < 6570) {
    int i = (blk - 6250) * 256 + t;
    if (i < 16384) {
      const float* W = (i < 8192) ? W0s : W0n;
      unsigned short* o = wt + (i < 8192 ? 0 : 8192);
      int j = i & 8191;
      int c = j >> 6, k = j & 63;
      o[j] = f2bf(W[k * 128 + c]);
    } else {
      int j = i - 16384;
      int sel = j >> 14;
      j &= 16383;
      const float* W = (sel == 0) ? W1s : (sel == 1) ? W1n : (sel == 2) ? W2s : W2n;
      unsigned short* o = wt + 16384 + sel * 16384;
      int c = j >> 7, k = j & 127;
      o[j] = f2bf(W[k * 128 + c]);
    }
  } else if (blk == 6570) {
    for (int i = t; i < 3 * 1024; i += 256) stats3[i] = 0.f;
  } else {
    // per-chunk histogram (merged k_hist)
    int hb = blk - 6571;
    int chunk = (E + BPART - 1) / BPART;
    int start = hb * chunk;
    int end = min(E, start + chunk);
    for (int b = t; b < NB; b += 256) hh[b] = 0;
    __syncthreads();
    for (int e = start + t; e < end; e += 256) atomicAdd(&hh[dst[e] >> 6], 1);
    __syncthreads();
    for (int b = t; b < NB; b += 256) hist[hb * NB + b] = hh[b];
  }
}

// ----------------- partition pass 2: per-bucket scan over chunks -----------
__global__ __launch_bounds__(256) void k_scan(const int* __restrict__ hist,
                                              int* __restrict__ base,
                                              int* __restrict__ gcursor) {
  int bb = blockIdx.x * 256 + threadIdx.x;
  if (bb >= NB) return;
  int run = 0;
  for (int r0 = 0; r0 < BPART; r0 += 16) {
    int v[16];
    #pragma unroll
    for (int u = 0; u < 16; u++) v[u] = hist[(r0 + u) * NB + bb];
    #pragma unroll
    for (int u = 0; u < 16; u++) { base[(r0 + u) * NB + bb] = run; run += v[u]; }
  }
  gcursor[bb] = run;
}

// ----------------- partition pass 3: scatter with LDS cursors --------------
__global__ __launch_bounds__(256) void k_scatter(const int* __restrict__ src,
                                                 const int* __restrict__ dst,
                                                 const int* __restrict__ base,
                                                 unsigned int* __restrict__ part, int E) {
  __shared__ int cur[NB];
  int t = threadIdx.x;
  int chunk = (E + BPART - 1) / BPART;
  int start = blockIdx.x * chunk;
  int end = min(E, start + chunk);
  for (int b = t; b < NB; b += 256) cur[b] = base[blockIdx.x * NB + b];
  __syncthreads();
  for (int e = start + t; e < end; e += 256) {
    int d = dst[e];
    int b = d >> 6;
    int pos = atomicAdd(&cur[b], 1);
    if ((unsigned)pos < (unsigned)CAP)
      part[(size_t)b * CAP + pos] = (unsigned)src[e] | ((unsigned)(d & 63) << 17);
  }
}

// ----------------- fused layer: CSR + gather(+BN) + 64x128 MFMA GEMM ------
// C[bucket rows] = bnrelu?(h[rows])@W1 + mean(bnrelu?(h[src]))@W2 + bias,
// + stats partials. neighT lives in LDS (XOR-swizzled); self A-frags read
// from global (L2-warm). No inter-block dependency.
template <int DIN, bool BN>
__global__ __launch_bounds__(512, 8) void k_layer(
    const unsigned short* __restrict__ h, const unsigned short* __restrict__ W1t,
    const unsigned short* __restrict__ W2t, const float* __restrict__ bias,
    const unsigned int* __restrict__ part, const int* __restrict__ gcursor,
    unsigned short* __restrict__ C, float* __restrict__ stats, int M,
    const float* __restrict__ statsP, const float* __restrict__ gamP,
    const float* __restrict__ betP) {
  __shared__ unsigned short neighT[64 * DIN];  // 16KB(128)/8KB(64); eraw overlay
  __shared__ unsigned eord[CAP];               // 4KB; redS/redQ overlay
  __shared__ unsigned short Bs[128 * 32];      // 8KB W k-chunk
  __shared__ int cnt[BSZ], offv[BSZ], cur[BSZ];
  __shared__ int stealCtr;
  __shared__ float sBN[128], tBN[128];
  unsigned* eraw = (unsigned*)neighT;          // dead before gather writes
  float* redS = (float*)eord;                  // [8][64]; eord dead at epilogue
  float* redQ = redS + 512;

  constexpr int SWZM = (DIN == 128) ? 15 : 7;  // chunk-swizzle mask
  int t = threadIdx.x;
  int lane = t & 63, w = t >> 6;
  int l15 = lane & 15, quad = lane >> 4;
  int bkt = blockIdx.x;
  int node0 = bkt * BSZ;
  int nn = min(BSZ, M - node0);

  // ---- init ----
  if (t < BSZ) cnt[t] = 0;
  if (t == 0) stealCtr = 0;
  if (BN && t < 128) bn_st(statsP, gamP, betP, t, sBN[t], tBN[t]);
  __syncthreads();

  // ---- CSR build (bucket-local counting sort) ----
  int ec = gcursor[bkt];
  ec = max(0, min(ec, CAP));
  for (int i = t; i < ec; i += 512) {
    unsigned wd = part[(size_t)bkt * CAP + i];
    eraw[i] = wd;
    atomicAdd(&cnt[wd >> 17], 1);
  }
  __syncthreads();
  if (t < BSZ) offv[t] = cnt[t];
  __syncthreads();
  #pragma unroll
  for (int o = 1; o < BSZ; o <<= 1) {
    int xv = 0;
    if (t < BSZ && t >= o) xv = offv[t - o];
    __syncthreads();
    if (t < BSZ) offv[t] += xv;
    __syncthreads();
  }
  if (t < BSZ) { int ex = offv[t] - cnt[t]; offv[t] = ex; cur[t] = ex; }
  __syncthreads();
  for (int i = t; i < ec; i += 512) {
    unsigned wd = eraw[i];
    int p = atomicAdd(&cur[wd >> 17], 1);
    eord[p] = wd & 0x1FFFF;
  }
  __syncthreads();  // eraw (neighT space) dead

  // ---- gather + mean (+BN per edge: free under memory bound) ----
  const int G = DIN / 8;
  int li = t & (G - 1);
  float sreg[8], treg[8];
  if (BN) {
    #pragma unroll
    for (int k = 0; k < 8; k++) { sreg[k] = sBN[li * 8 + k]; treg[k] = tBN[li * 8 + k]; }
  }
  for (;;) {
    int nd0 = 0;
    if (li == 0) nd0 = atomicAdd(&stealCtr, 1);
    int nd = __shfl(nd0, 0, G);
    if (nd >= BSZ) break;
    u16x8 o;
    if (nd >= nn) {
      #pragma unroll
      for (int k = 0; k < 8; k++) o[k] = 0;
    } else {
      int s = offv[nd], c = cnt[nd];
      int e = s + c;
      float acc[8] = {0.f, 0.f, 0.f, 0.f, 0.f, 0.f, 0.f, 0.f};
      int j = s;
      for (; j + 2 <= e; j += 2) {
        int sn0 = eord[j], sn1 = eord[j + 1];
        u16x8 v0 = *(const u16x8*)&h[(size_t)sn0 * DIN + li * 8];
        u16x8 v1 = *(const u16x8*)&h[(size_t)sn1 * DIN + li * 8];
        if (BN) {
          #pragma unroll
          for (int k = 0; k < 8; k++)
            acc[k] += fmaxf(fmaf(bf2f(v0[k]), sreg[k], treg[k]), 0.f)
                    + fmaxf(fmaf(bf2f(v1[k]), sreg[k], treg[k]), 0.f);
        } else {
          #pragma unroll
          for (int k = 0; k < 8; k++) acc[k] += bf2f(v0[k]) + bf2f(v1[k]);
        }
      }
      if (j < e) {
        int sn = eord[j];
        u16x8 v = *(const u16x8*)&h[(size_t)sn * DIN + li * 8];
        if (BN) {
          #pragma unroll
          for (int k = 0; k < 8; k++)
            acc[k] += fmaxf(fmaf(bf2f(v[k]), sreg[k], treg[k]), 0.f);
        } else {
          #pragma unroll
          for (int k = 0; k < 8; k++) acc[k] += bf2f(v[k]);
        }
      }
      float inv = 1.0f / fmaxf((float)c, 1.0f);
      #pragma unroll
      for (int k = 0; k < 8; k++) o[k] = f2bf(acc[k] * inv);
    }
    *(u16x8*)&neighT[nd * DIN + ((li * 8) ^ ((nd & SWZM) << 3))] = o;
  }
  __syncthreads();  // neighT complete

  // ---- GEMM: 64 rows x 128 cols; wave (strip=w>>1, colhalf=w&1) ----
  const int strip = w >> 1;
  const int ch = w & 1;
  const int row = strip * 16 + l15;
  f32x4 acc4[4];
  #pragma unroll
  for (int ct = 0; ct < 4; ct++) acc4[ct] = (f32x4){0.f, 0.f, 0.f, 0.f};

  #pragma unroll
  for (int half = 0; half < 2; half++) {
    const unsigned short* Wt = half ? W2t : W1t;
    for (int k0 = 0; k0 < DIN; k0 += 32) {
      // stage Bs = Wt[:,k0:k0+32] (128 out-rows x 32 k): one shot, 512x16B
      {
        int r = t >> 2, prt = t & 3;
        gload_lds16(&Wt[(size_t)r * DIN + k0 + prt * 8], &Bs[(w * 64) * 8]);
      }
      __syncthreads();  // Bs ready (drains vmcnt)
      bf16x8 af;
      {
        u16x8 v;
        if (half == 0) {
          v = *(const u16x8*)&h[(size_t)(node0 + row) * DIN + k0 + quad * 8];
          if (BN) {
            #pragma unroll
            for (int j = 0; j < 8; j++) {
              int c = k0 + quad * 8 + j;
              v[j] = f2bf(fmaxf(fmaf(bf2f(v[j]), sBN[c], tBN[c]), 0.f));
            }
          }
        } else {
          int cc = k0 + quad * 8;
          v = *(const u16x8*)&neighT[row * DIN + (cc ^ ((row & SWZM) << 3))];
        }
        af = *(bf16x8*)&v;
      }
      #pragma unroll
      for (int ct = 0; ct < 4; ct++) {
        bf16x8 bfr = *(const bf16x8*)&Bs[(ch * 64 + ct * 16 + l15) * 32 + quad * 8];
        acc4[ct] = __builtin_amdgcn_mfma_f32_16x16x32_bf16(af, bfr, acc4[ct], 0, 0, 0);
      }
      __syncthreads();  // Bs consumed before restage
    }
  }

  // ---- epilogue: bias, C write, stats partials ----
  float bcol[4], ls[4], lq[4];
  #pragma unroll
  for (int ct = 0; ct < 4; ct++) {
    bcol[ct] = bias[ch * 64 + ct * 16 + l15];
    ls[ct] = 0.f; lq[ct] = 0.f;
  }
  #pragma unroll
  for (int r = 0; r < 4; r++) {
    int orow = node0 + strip * 16 + quad * 4 + r;
    if (orow < M) {
      #pragma unroll
      for (int ct = 0; ct < 4; ct++) {
        float v = acc4[ct][r] + bcol[ct];
        C[(size_t)orow * 128 + ch * 64 + ct * 16 + l15] = f2bf(v);
        ls[ct] += v; lq[ct] += v * v;
      }
    }
  }
  #pragma unroll
  for (int ct = 0; ct < 4; ct++) {  // reduce over quads (rows of strip)
    ls[ct] += __shfl_xor(ls[ct], 16); ls[ct] += __shfl_xor(ls[ct], 32);
    lq[ct] += __shfl_xor(lq[ct], 16); lq[ct] += __shfl_xor(lq[ct], 32);
  }
  if (quad == 0) {
    #pragma unroll
    for (int ct = 0; ct < 4; ct++) {
      redS[w * 64 + ct * 16 + l15] = ls[ct];
      redQ[w * 64 + ct * 16 + l15] = lq[ct];
    }
  }
  __syncthreads();
  if (t < 128) {
    int ch2 = t >> 6, c6 = t & 63;
    float s = 0.f, q = 0.f;
    #pragma unroll
    for (int st = 0; st < 4; st++) {
      s += redS[(st * 2 + ch2) * 64 + c6];
      q += redQ[(st * 2 + ch2) * 64 + c6];
    }
    int rep = (bkt & 3) * 256;  // 4 replicas
    atomicAdd(&stats[rep + t], s);
    atomicAdd(&stats[rep + 128 + t], q);
  }
}

// ----------------- fused BN + ReLU + classifier -----------------
__global__ void k_final(const unsigned short* __restrict__ h,
                        const float* __restrict__ statsP, const float* __restrict__ gamP,
                        const float* __restrict__ betP, const float* __restrict__ Wc,
                        const float* __restrict__ bc, float* __restrict__ out, int n) {
  int lane = threadIdx.x & 63;
  int row = blockIdx.x * (blockDim.x >> 6) + (threadIdx.x >> 6);
  if (row >= n) return;
  float acc0 = 0.f, acc1 = 0.f;
  #pragma unroll
  for (int m = 0; m < 2; m++) {
    int c = lane + 64 * m;
    float s, tt;
    bn_st(statsP, gamP, betP, c, s, tt);
    float v = bf2f(h[(size_t)row * 128 + c]);
    v = fmaxf(fmaf(v, s, tt), 0.f);
    acc0 += v * Wc[c * 2 + 0];
    acc1 += v * Wc[c * 2 + 1];
  }
  #pragma unroll
  for (int off = 32; off > 0; off >>= 1) {
    acc0 += __shfl_down(acc0, off);
    acc1 += __shfl_down(acc1, off);
  }
  if (lane == 0) {
    out[row * 2 + 0] = acc0 + bc[0];
    out[row * 2 + 1] = acc1 + bc[1];
  }
}

extern "C" void kernel_launch(void* const* d_in, const int* in_sizes, int n_in,
                              void* d_out, int out_size, void* d_ws, size_t ws_size,
                              hipStream_t stream) {
  const float* x   = (const float*)d_in[0];
  const int* src   = (const int*)d_in[1];
  const int* dst   = (const int*)d_in[2];
  const float* Wself[3] = {(const float*)d_in[3], (const float*)d_in[8],  (const float*)d_in[13]};
  const float* bself[3] = {(const float*)d_in[4], (const float*)d_in[9],  (const float*)d_in[14]};
  const float* Wngh[3]  = {(const float*)d_in[5], (const float*)d_in[10], (const float*)d_in[15]};
  const float* gam[3]   = {(const float*)d_in[6], (const float*)d_in[11], (const float*)d_in[16]};
  const float* bet[3]   = {(const float*)d_in[7], (const float*)d_in[12], (const float*)d_in[17]};
  const float* Wc = (const float*)d_in[18];
  const float* bc = (const float*)d_in[19];
  float* out = (float*)d_out;

  const int N = N_NODES, E = N_EDGES;

  unsigned short* x16 = (unsigned short*)d_ws;        // N*64
  unsigned short* b0  = x16 + (size_t)N * 64;         // N*128 (slack)
  unsigned short* b1  = b0 + (size_t)N * 128;
  unsigned short* b2  = b1 + (size_t)N * 128;
  unsigned short* wt  = b2 + (size_t)N * 128;         // 81920
  unsigned int* part  = (unsigned int*)(wt + 81920);  // NB*CAP
  int* gcursor  = (int*)(part + (size_t)NB * CAP);    // NB
  float* stats3 = (float*)(gcursor + NB);             // 3*1024

  // hist/base (BPART*NB ints = 1.6MB each) alias into b1 — b1 is first
  // written by layer0's k_layer, stream-ordered after scan/scatter.
  int* hist = (int*)b1;
  int* base = hist + (size_t)BPART * NB;

  // ---- prep: x->bf16, weights, stats zero, edge hist ----
  k_prep<<<6571 + BPART, 256, 0, stream>>>(
      x, x16, Wself[0], Wngh[0], Wself[1], Wngh[1], Wself[2], Wngh[2],
      wt, stats3, dst, hist, E);

  // ---- partition: scan -> scatter ----
  k_scan<<<(NB + 255) / 256, 256, 0, stream>>>(hist, base, gcursor);
  k_scatter<<<BPART, 256, 0, stream>>>(src, dst, base, part, E);

  // ---- fused layers ----
  k_layer<64, false><<<NB, 512, 0, stream>>>(
      x16, wt + 0, wt + 8192, bself[0], part, gcursor, b1, stats3 + 0, N,
      nullptr, nullptr, nullptr);
  k_layer<128, true><<<NB, 512, 0, stream>>>(
      b1, wt + 16384, wt + 32768, bself[1], part, gcursor, b2, stats3 + 1024, N,
      stats3 + 0, gam[0], bet[0]);
  k_layer<128, true><<<NB, 512, 0, stream>>>(
      b2, wt + 49152, wt + 65536, bself[2], part, gcursor, b1, stats3 + 2048, N,
      stats3 + 1024, gam[1], bet[1]);

  // ---- fused BN2 + ReLU + classifier ----
  k_final<<<(N + 3) / 4, 256, 0, stream>>>(b1, stats3 + 2048, gam[2], bet[2],
                                           Wc, bc, out, N);
}